// Round 1
// baseline (3185.324 us; speedup 1.0000x reference)
//
#include <hip/hip_runtime.h>
#include <hip/hip_fp16.h>

// Sinkhorn OT loss, N=8192, D=128.
// K = exp(-C/eps) materialized once in fp16 (128 MB, fits Infinity Cache).
// 50 iterations: u = mu/(K v + stab); v = nu/(K^T u + stab).
// Loss = sum_ij u_i K_ij v_j * (-eps * ln K_ij).

constexpr int   N      = 8192;
constexpr int   D      = 128;
constexpr float EPSV   = 0.05f;
constexpr int   NITER  = 50;
constexpr float STABV  = 1e-8f;
constexpr int   NCHUNK = 128;            // row chunks for col-matvec partials
constexpr float NEG_LOG2E_OVER_EPS = -1.4426950408889634f / EPSV; // exp(-c/eps)=exp2(c*this)
constexpr float NEG_EPS_LN2 = -EPSV * 0.6931471805599453f;        // C = NEG_EPS_LN2 * log2(K)

// ---------------- init: x2, y2, v=1, out=0 ----------------
__global__ __launch_bounds__(256) void init_kernel(
    const float* __restrict__ X, const float* __restrict__ Y,
    float* __restrict__ x2, float* __restrict__ y2,
    float* __restrict__ v, float* __restrict__ out)
{
    int tid  = threadIdx.x;
    int gtid = blockIdx.x * 256 + tid;
    if (gtid < N) v[gtid] = 1.0f;
    if (gtid == 0) out[0] = 0.0f;

    // one wave per row, 4 waves/block, 2N rows total; grid = 2N/4 = 4096
    int wave = tid >> 6, lane = tid & 63;
    int row = blockIdx.x * 4 + wave;
    const float* src = (row < N) ? (X + (size_t)row * D)
                                 : (Y + (size_t)(row - N) * D);
    float a = src[lane], b = src[lane + 64];
    float s = a * a + b * b;
    #pragma unroll
    for (int off = 32; off > 0; off >>= 1) s += __shfl_down(s, off, 64);
    if (lane == 0) {
        if (row < N) x2[row] = s; else y2[row - N] = s;
    }
}

// ---------------- K matrix: tiled fp32 GEMM + exp, store fp16 ----------------
__global__ __launch_bounds__(256) void kmat_kernel(
    const float* __restrict__ X, const float* __restrict__ Y,
    const float* __restrict__ x2, const float* __restrict__ y2,
    __half* __restrict__ Km)
{
    __shared__ float As[64][17];
    __shared__ float Bs[64][17];
    int t  = threadIdx.x;
    int tx = t & 15, ty = t >> 4;
    int rowBase = blockIdx.y * 64;
    int colBase = blockIdx.x * 64;

    float acc[4][4] = {};
    for (int k0 = 0; k0 < D; k0 += 16) {
        #pragma unroll
        for (int l = 0; l < 4; ++l) {
            int e = l * 256 + t;
            int r = e >> 4, kk = e & 15;
            As[r][kk] = X[(size_t)(rowBase + r) * D + k0 + kk];
            Bs[r][kk] = Y[(size_t)(colBase + r) * D + k0 + kk];
        }
        __syncthreads();
        #pragma unroll
        for (int kk = 0; kk < 16; ++kk) {
            float a[4], b[4];
            #pragma unroll
            for (int i = 0; i < 4; ++i) a[i] = As[ty * 4 + i][kk];
            #pragma unroll
            for (int j = 0; j < 4; ++j) b[j] = Bs[tx * 4 + j][kk];
            #pragma unroll
            for (int i = 0; i < 4; ++i)
                #pragma unroll
                for (int j = 0; j < 4; ++j)
                    acc[i][j] += a[i] * b[j];
        }
        __syncthreads();
    }

    #pragma unroll
    for (int i = 0; i < 4; ++i) {
        int row = rowBase + ty * 4 + i;
        float xs = x2[row];
        __half2* orow = (__half2*)(Km + (size_t)row * N + colBase + tx * 4);
        #pragma unroll
        for (int j = 0; j < 4; j += 2) {
            int col = colBase + tx * 4 + j;
            float c0 = fmaxf(xs + y2[col]     - 2.f * acc[i][j],     0.f);
            float c1 = fmaxf(xs + y2[col + 1] - 2.f * acc[i][j + 1], 0.f);
            float k0 = exp2f(c0 * NEG_LOG2E_OVER_EPS);
            float k1 = exp2f(c1 * NEG_LOG2E_OVER_EPS);
            orow[j >> 1] = __floats2half2_rn(k0, k1);
        }
    }
}

// ---------------- u = mu / (K v + stab); one block per row ----------------
__global__ __launch_bounds__(256) void rowmv_kernel(
    const __half* __restrict__ Km, const float* __restrict__ v,
    float* __restrict__ u)
{
    int row = blockIdx.x;
    const __half* Kr = Km + (size_t)row * N;
    int t = threadIdx.x;
    float s = 0.f;
    #pragma unroll
    for (int c = 0; c < 4; ++c) {
        int j = c * 2048 + t * 8;
        float4 raw = *(const float4*)(Kr + j);      // 8 halves
        __half2 h0 = *(__half2*)&raw.x;
        __half2 h1 = *(__half2*)&raw.y;
        __half2 h2 = *(__half2*)&raw.z;
        __half2 h3 = *(__half2*)&raw.w;
        float2 k0 = __half22float2(h0), k1 = __half22float2(h1);
        float2 k2 = __half22float2(h2), k3 = __half22float2(h3);
        const float4* vp = (const float4*)(v + j);
        float4 v0 = vp[0], v1 = vp[1];
        s += k0.x * v0.x + k0.y * v0.y + k1.x * v0.z + k1.y * v0.w
           + k2.x * v1.x + k2.y * v1.y + k3.x * v1.z + k3.y * v1.w;
    }
    #pragma unroll
    for (int off = 32; off > 0; off >>= 1) s += __shfl_down(s, off, 64);
    __shared__ float ws[4];
    if ((t & 63) == 0) ws[t >> 6] = s;
    __syncthreads();
    if (t == 0) {
        float tot = ws[0] + ws[1] + ws[2] + ws[3];
        u[row] = (1.0f / N) / (tot + STABV);
    }
}

// ---------------- partial K^T u: grid (4, NCHUNK); block owns 64 rows x 2048 cols ----------------
__global__ __launch_bounds__(256) void colmv_kernel(
    const __half* __restrict__ Km, const float* __restrict__ u,
    float* __restrict__ tp)
{
    int t  = threadIdx.x;
    int j0 = blockIdx.x * 2048 + t * 8;
    int i0 = blockIdx.y * (N / NCHUNK);
    float acc[8] = {};
    #pragma unroll 4
    for (int i = i0; i < i0 + (N / NCHUNK); ++i) {
        float4 raw = *(const float4*)(Km + (size_t)i * N + j0);
        float ui = u[i];
        __half2 h0 = *(__half2*)&raw.x;
        __half2 h1 = *(__half2*)&raw.y;
        __half2 h2 = *(__half2*)&raw.z;
        __half2 h3 = *(__half2*)&raw.w;
        float2 k0 = __half22float2(h0), k1 = __half22float2(h1);
        float2 k2 = __half22float2(h2), k3 = __half22float2(h3);
        acc[0] += ui * k0.x; acc[1] += ui * k0.y;
        acc[2] += ui * k1.x; acc[3] += ui * k1.y;
        acc[4] += ui * k2.x; acc[5] += ui * k2.y;
        acc[6] += ui * k3.x; acc[7] += ui * k3.y;
    }
    float4* o = (float4*)(tp + (size_t)blockIdx.y * N + j0);
    o[0] = make_float4(acc[0], acc[1], acc[2], acc[3]);
    o[1] = make_float4(acc[4], acc[5], acc[6], acc[7]);
}

// ---------------- v = nu / (sum partials + stab) ----------------
__global__ __launch_bounds__(256) void colfin_kernel(
    const float* __restrict__ tp, float* __restrict__ v)
{
    int j = blockIdx.x * 256 + threadIdx.x;   // grid 32
    float s = 0.f;
    #pragma unroll 8
    for (int c = 0; c < NCHUNK; ++c) s += tp[(size_t)c * N + j];
    v[j] = (1.0f / N) / (s + STABV);
}

// ---------------- loss = sum u_i K_ij v_j * (-eps ln K_ij) ----------------
__global__ __launch_bounds__(256) void loss_kernel(
    const __half* __restrict__ Km, const float* __restrict__ u,
    const float* __restrict__ vv, float* __restrict__ out)
{
    int t  = threadIdx.x;
    int j0 = blockIdx.x * 1024 + t * 4;       // grid (8, 32)
    int i0 = blockIdx.y * 256;
    float a0 = 0, a1 = 0, a2 = 0, a3 = 0;
    #pragma unroll 4
    for (int i = i0; i < i0 + 256; ++i) {
        float2 raw = *(const float2*)(Km + (size_t)i * N + j0);  // 4 halves
        float ui = u[i];
        __half2 h0 = *(__half2*)&raw.x;
        __half2 h1 = *(__half2*)&raw.y;
        float2 k0 = __half22float2(h0), k1 = __half22float2(h1);
        a0 += ui * k0.x * __log2f(k0.x);
        a1 += ui * k0.y * __log2f(k0.y);
        a2 += ui * k1.x * __log2f(k1.x);
        a3 += ui * k1.y * __log2f(k1.y);
    }
    float s = NEG_EPS_LN2 * (a0 * vv[j0] + a1 * vv[j0 + 1]
                           + a2 * vv[j0 + 2] + a3 * vv[j0 + 3]);
    #pragma unroll
    for (int off = 32; off > 0; off >>= 1) s += __shfl_down(s, off, 64);
    __shared__ float ws[4];
    if ((t & 63) == 0) ws[t >> 6] = s;
    __syncthreads();
    if (t == 0) atomicAdd(out, ws[0] + ws[1] + ws[2] + ws[3]);
}

extern "C" void kernel_launch(void* const* d_in, const int* in_sizes, int n_in,
                              void* d_out, int out_size, void* d_ws, size_t ws_size,
                              hipStream_t stream) {
    const float* X = (const float*)d_in[0];
    const float* Y = (const float*)d_in[1];
    float* out = (float*)d_out;

    char* ws = (char*)d_ws;
    __half* Km = (__half*)ws;
    size_t off = (size_t)N * N * sizeof(__half);   // 128 MB
    float* x2 = (float*)(ws + off); off += (size_t)N * 4;
    float* y2 = (float*)(ws + off); off += (size_t)N * 4;
    float* u  = (float*)(ws + off); off += (size_t)N * 4;
    float* v  = (float*)(ws + off); off += (size_t)N * 4;
    float* tp = (float*)(ws + off);                // NCHUNK*N*4 = 4 MB

    init_kernel<<<4096, 256, 0, stream>>>(X, Y, x2, y2, v, out);
    kmat_kernel<<<dim3(N / 64, N / 64), 256, 0, stream>>>(X, Y, x2, y2, Km);
    for (int it = 0; it < NITER; ++it) {
        rowmv_kernel<<<N, 256, 0, stream>>>(Km, v, u);
        colmv_kernel<<<dim3(4, NCHUNK), 256, 0, stream>>>(Km, u, tp);
        colfin_kernel<<<N / 256, 256, 0, stream>>>(tp, v);
    }
    loss_kernel<<<dim3(8, 32), 256, 0, stream>>>(Km, u, v, out);
}

// Round 2
// 1680.780 us; speedup vs baseline: 1.8951x; 1.8951x over previous
//
#include <hip/hip_runtime.h>
#include <hip/hip_fp16.h>

// Sinkhorn OT loss, N=8192, D=128.
// K = exp(-C/eps) materialized once in fp8 e4m3 (64 MB, LLC-resident).
// 50 iterations, each ONE pass over K: fused kernel computes u (row matvec)
// then re-reads its tile from L2 to emit column partials (K^T u).
// Loss = sum u_i K_ij v_j * (-eps * ln K_ij).

constexpr int   N      = 8192;
constexpr int   D      = 128;
constexpr float EPSV   = 0.05f;
constexpr int   NITER  = 50;
constexpr float STABV  = 1e-8f;
constexpr float MU     = 1.0f / N;
constexpr float NU     = 1.0f / N;
constexpr float NEG_LOG2E_OVER_EPS = -1.4426950408889634f / EPSV; // exp(-c/eps)=exp2(c*this)
constexpr float NEG_EPS_LN2 = -EPSV * 0.6931471805599453f;        // C = NEG_EPS_LN2 * log2(K)

typedef float    f32x2  __attribute__((ext_vector_type(2)));
typedef float    f32x4v __attribute__((ext_vector_type(4)));
typedef _Float16 half4v __attribute__((ext_vector_type(4)));
typedef _Float16 half8v __attribute__((ext_vector_type(8)));

__device__ __forceinline__ void fp8x4_to_f32(unsigned w, float* o) {
    f32x2 lo = __builtin_amdgcn_cvt_pk_f32_fp8((int)w, false);
    f32x2 hi = __builtin_amdgcn_cvt_pk_f32_fp8((int)w, true);
    o[0] = lo[0]; o[1] = lo[1]; o[2] = hi[0]; o[3] = hi[1];
}

// ---------------- init: x2, y2, v=1, out=0 ----------------
__global__ __launch_bounds__(256) void init_kernel(
    const float* __restrict__ X, const float* __restrict__ Y,
    float* __restrict__ x2, float* __restrict__ y2,
    float* __restrict__ v, float* __restrict__ out)
{
    int tid  = threadIdx.x;
    int gtid = blockIdx.x * 256 + tid;
    if (gtid < N) v[gtid] = 1.0f;
    if (gtid == 0) out[0] = 0.0f;

    int wave = tid >> 6, lane = tid & 63;
    int row = blockIdx.x * 4 + wave;
    const float* src = (row < N) ? (X + (size_t)row * D)
                                 : (Y + (size_t)(row - N) * D);
    float a = src[lane], b = src[lane + 64];
    float s = a * a + b * b;
    #pragma unroll
    for (int off = 32; off > 0; off >>= 1) s += __shfl_down(s, off, 64);
    if (lane == 0) {
        if (row < N) x2[row] = s; else y2[row - N] = s;
    }
}

// ---------------- K matrix: fp16 MFMA GEMM + exp, store fp8 ----------------
// 128x128 tile/block, D=128 = whole K-dim in one LDS tile. XOR-swizzled LDS.
__global__ __launch_bounds__(256) void kmat_kernel(
    const float* __restrict__ X, const float* __restrict__ Y,
    const float* __restrict__ x2, const float* __restrict__ y2,
    unsigned char* __restrict__ Km)
{
    __shared__ _Float16 Xs[128 * 128];   // 32 KB, swizzled
    __shared__ _Float16 Ys[128 * 128];   // 32 KB
    int t = threadIdx.x;
    int rowBase = blockIdx.y * 128, colBase = blockIdx.x * 128;

    // stage: fp32 -> fp16, fully coalesced global float4, b64 LDS writes
    #pragma unroll
    for (int l = 0; l < 16; ++l) {
        int e = l * 256 + t;
        int r = e >> 5, c4 = e & 31;              // 32 float4 per row
        int sw = r * 128 + ((((c4 >> 1) ^ (r & 7)) << 3) + (c4 & 1) * 4);
        float4 a = *(const float4*)(X + (size_t)(rowBase + r) * D + c4 * 4);
        float4 b = *(const float4*)(Y + (size_t)(colBase + r) * D + c4 * 4);
        half4v ha = { (_Float16)a.x, (_Float16)a.y, (_Float16)a.z, (_Float16)a.w };
        half4v hb = { (_Float16)b.x, (_Float16)b.y, (_Float16)b.z, (_Float16)b.w };
        *(half4v*)&Xs[sw] = ha;
        *(half4v*)&Ys[sw] = hb;
    }
    __syncthreads();

    int wave = t >> 6, lane = t & 63;
    int wr = (wave >> 1) * 64, wc = (wave & 1) * 64;   // 2x2 wave grid
    int m = lane & 15, quad = lane >> 4;

    f32x4v acc[4][4];
    #pragma unroll
    for (int i = 0; i < 4; ++i)
        #pragma unroll
        for (int j = 0; j < 4; ++j)
            acc[i][j] = (f32x4v){0.f, 0.f, 0.f, 0.f};

    #pragma unroll
    for (int kk = 0; kk < 4; ++kk) {
        half8v af[4], bf[4];
        int uidx = kk * 4 + quad;
        #pragma unroll
        for (int i = 0; i < 4; ++i) {
            int Ra = wr + i * 16 + m;
            int Rb = wc + i * 16 + m;
            af[i] = *(const half8v*)&Xs[Ra * 128 + ((uidx ^ (Ra & 7)) << 3)];
            bf[i] = *(const half8v*)&Ys[Rb * 128 + ((uidx ^ (Rb & 7)) << 3)];
        }
        #pragma unroll
        for (int i = 0; i < 4; ++i)
            #pragma unroll
            for (int j = 0; j < 4; ++j)
                acc[i][j] = __builtin_amdgcn_mfma_f32_16x16x32_f16(af[i], bf[j], acc[i][j], 0, 0, 0);
    }

    // epilogue: C = x2+y2-2*dot, K = exp2(C * -log2e/eps), store fp8 bytes
    float y2c[4];
    #pragma unroll
    for (int j = 0; j < 4; ++j) y2c[j] = y2[colBase + wc + j * 16 + m];

    #pragma unroll
    for (int i = 0; i < 4; ++i) {
        #pragma unroll
        for (int rr = 0; rr < 4; ++rr) {
            int row = rowBase + wr + i * 16 + quad * 4 + rr;
            float xs = x2[row];
            size_t ro = (size_t)row * N + colBase + wc + m;
            #pragma unroll
            for (int j = 0; j < 4; j += 2) {
                float c0 = fmaxf(xs + y2c[j]     - 2.f * acc[i][j][rr],     0.f);
                float c1 = fmaxf(xs + y2c[j + 1] - 2.f * acc[i][j + 1][rr], 0.f);
                float k0 = exp2f(c0 * NEG_LOG2E_OVER_EPS);
                float k1 = exp2f(c1 * NEG_LOG2E_OVER_EPS);
                unsigned p = (unsigned)__builtin_amdgcn_cvt_pk_fp8_f32(k0, k1, 0, false);
                Km[ro + j * 16]      = (unsigned char)(p & 0xff);
                Km[ro + j * 16 + 16] = (unsigned char)((p >> 8) & 0xff);
            }
        }
    }
}

// ---------------- fused iteration: u = mu/(K v + stab); tp = row-chunk partials of K^T u ----------------
// 512 blocks x 16 rows. Pass A: wave per 4 rows, v in padded LDS.
// Pass B: re-read tile (L2-hot), thread owns 32 cols, write partials.
__global__ __launch_bounds__(256) void iter_kernel(
    const unsigned char* __restrict__ Km, const float* __restrict__ v,
    float* __restrict__ u, float* __restrict__ tp)
{
    __shared__ float vs[10240];   // 16-float groups padded +4 -> bank-balanced b128
    __shared__ float us[16];
    int t = threadIdx.x;

    #pragma unroll
    for (int l = 0; l < 8; ++l) {
        int col = l * 1024 + t * 4;
        *(float4*)&vs[(col >> 4) * 20 + (col & 15)] = *(const float4*)(v + col);
    }
    __syncthreads();

    int wave = t >> 6, lane = t & 63;
    int r0 = blockIdx.x * 16 + wave * 4;
    const unsigned char* base = Km + (size_t)r0 * N;

    float a[4] = {0.f, 0.f, 0.f, 0.f};
    for (int c = 0; c < 8; ++c) {
        int col = c * 1024 + lane * 16;          // 1 KB/wave contiguous
        int vi = (col >> 4) * 20;
        float4 v0 = *(const float4*)&vs[vi];
        float4 v1 = *(const float4*)&vs[vi + 4];
        float4 v2 = *(const float4*)&vs[vi + 8];
        float4 v3 = *(const float4*)&vs[vi + 12];
        #pragma unroll
        for (int rr = 0; rr < 4; ++rr) {
            uint4 raw = *(const uint4*)(base + (size_t)rr * N + col);
            float k[16];
            fp8x4_to_f32(raw.x, k);     fp8x4_to_f32(raw.y, k + 4);
            fp8x4_to_f32(raw.z, k + 8); fp8x4_to_f32(raw.w, k + 12);
            a[rr] += k[0]*v0.x + k[1]*v0.y + k[2]*v0.z + k[3]*v0.w
                   + k[4]*v1.x + k[5]*v1.y + k[6]*v1.z + k[7]*v1.w
                   + k[8]*v2.x + k[9]*v2.y + k[10]*v2.z + k[11]*v2.w
                   + k[12]*v3.x + k[13]*v3.y + k[14]*v3.z + k[15]*v3.w;
        }
    }
    #pragma unroll
    for (int rr = 0; rr < 4; ++rr) {
        float s = a[rr];
        #pragma unroll
        for (int off = 32; off > 0; off >>= 1) s += __shfl_down(s, off, 64);
        if (lane == 0) {
            float ur = MU / (s + STABV);
            us[wave * 4 + rr] = ur;
            u[r0 + rr] = ur;
        }
    }
    __syncthreads();

    // pass B: tile is L2-hot; thread owns cols [t*16,+16) and [4096+t*16,+16)
    const unsigned char* kb = Km + (size_t)(blockIdx.x * 16) * N;
    float cacc[32];
    #pragma unroll
    for (int q = 0; q < 32; ++q) cacc[q] = 0.f;
    for (int r = 0; r < 16; ++r) {
        float ur = us[r];
        uint4 raw0 = *(const uint4*)(kb + (size_t)r * N + t * 16);
        uint4 raw1 = *(const uint4*)(kb + (size_t)r * N + 4096 + t * 16);
        float k[16];
        fp8x4_to_f32(raw0.x, k);     fp8x4_to_f32(raw0.y, k + 4);
        fp8x4_to_f32(raw0.z, k + 8); fp8x4_to_f32(raw0.w, k + 12);
        #pragma unroll
        for (int q = 0; q < 16; ++q) cacc[q] += ur * k[q];
        fp8x4_to_f32(raw1.x, k);     fp8x4_to_f32(raw1.y, k + 4);
        fp8x4_to_f32(raw1.z, k + 8); fp8x4_to_f32(raw1.w, k + 12);
        #pragma unroll
        for (int q = 0; q < 16; ++q) cacc[16 + q] += ur * k[q];
    }
    float* o0 = tp + (size_t)blockIdx.x * N + t * 16;
    float* o1 = o0 + 4096;
    #pragma unroll
    for (int q = 0; q < 4; ++q) {
        ((float4*)o0)[q] = make_float4(cacc[q*4], cacc[q*4+1], cacc[q*4+2], cacc[q*4+3]);
        ((float4*)o1)[q] = make_float4(cacc[16+q*4], cacc[16+q*4+1], cacc[16+q*4+2], cacc[16+q*4+3]);
    }
}

// ---------------- v = nu / (sum of 512 partials + stab) ----------------
__global__ __launch_bounds__(256) void colfin_kernel(
    const float* __restrict__ tp, float* __restrict__ v)
{
    int t = threadIdx.x;
    int col = blockIdx.x * 32 + (t & 31);   // grid 256
    int cp = t >> 5;                         // 8 chunk groups
    float s = 0.f;
    #pragma unroll 4
    for (int k = 0; k < 64; ++k) s += tp[(size_t)(cp * 64 + k) * N + col];
    __shared__ float red[256];
    red[t] = s; __syncthreads();
    if (t < 128) red[t] += red[t + 128];
    __syncthreads();
    if (t < 64)  red[t] += red[t + 64];
    __syncthreads();
    if (t < 32)  v[blockIdx.x * 32 + t] = NU / (red[t] + red[t + 32] + STABV);
}

// ---------------- loss = sum u_i K_ij v_j * (-eps ln K_ij) ----------------
__global__ __launch_bounds__(256) void loss_kernel(
    const unsigned char* __restrict__ Km, const float* __restrict__ u,
    const float* __restrict__ vv, float* __restrict__ out)
{
    int t = threadIdx.x;
    int j0 = blockIdx.x * 2048 + t * 8;     // grid (4, 128)
    int i0 = blockIdx.y * 64;
    float vj[8];
    *(float4*)vj       = *(const float4*)(vv + j0);
    *(float4*)(vj + 4) = *(const float4*)(vv + j0 + 4);
    float a[8] = {};
    for (int i = 0; i < 64; ++i) {
        float ui = u[i0 + i];
        uint2 raw = *(const uint2*)(Km + (size_t)(i0 + i) * N + j0);
        float k[8];
        fp8x4_to_f32(raw.x, k); fp8x4_to_f32(raw.y, k + 4);
        #pragma unroll
        for (int q = 0; q < 8; ++q) {
            float kk = fmaxf(k[q], 6e-8f);   // guard log2(0)
            a[q] += ui * kk * __log2f(kk);
        }
    }
    float s = 0.f;
    #pragma unroll
    for (int q = 0; q < 8; ++q) s += a[q] * vj[q];
    s *= NEG_EPS_LN2;
    #pragma unroll
    for (int off = 32; off > 0; off >>= 1) s += __shfl_down(s, off, 64);
    __shared__ float ws[4];
    if ((t & 63) == 0) ws[t >> 6] = s;
    __syncthreads();
    if (t == 0) atomicAdd(out, ws[0] + ws[1] + ws[2] + ws[3]);
}

extern "C" void kernel_launch(void* const* d_in, const int* in_sizes, int n_in,
                              void* d_out, int out_size, void* d_ws, size_t ws_size,
                              hipStream_t stream) {
    const float* X = (const float*)d_in[0];
    const float* Y = (const float*)d_in[1];
    float* out = (float*)d_out;

    char* ws = (char*)d_ws;
    unsigned char* Km = (unsigned char*)ws;
    size_t off = (size_t)N * N;                    // 64 MB fp8
    float* x2 = (float*)(ws + off); off += (size_t)N * 4;
    float* y2 = (float*)(ws + off); off += (size_t)N * 4;
    float* u  = (float*)(ws + off); off += (size_t)N * 4;
    float* v  = (float*)(ws + off); off += (size_t)N * 4;
    float* tp = (float*)(ws + off);                // 512*N*4 = 16 MB

    init_kernel<<<4096, 256, 0, stream>>>(X, Y, x2, y2, v, out);
    kmat_kernel<<<dim3(N / 128, N / 128), 256, 0, stream>>>(X, Y, x2, y2, Km);
    for (int it = 0; it < NITER; ++it) {
        iter_kernel<<<512, 256, 0, stream>>>(Km, v, u, tp);
        colfin_kernel<<<256, 256, 0, stream>>>(tp, v);
    }
    loss_kernel<<<dim3(4, 128), 256, 0, stream>>>(Km, u, v, out);
}